// Round 8
// baseline (1418.818 us; speedup 1.0000x reference)
//
#include <hip/hip_runtime.h>
#include <hip/hip_bf16.h>
#include <math.h>

// Problem constants
#define BB 16
#define TT 512
#define FF 40
#define CC 256
#define HH 256
#define GG 768   // 3*H
#define NB 16

typedef _Float16 f16;
typedef __attribute__((ext_vector_type(8))) _Float16 f16x8;
typedef __attribute__((ext_vector_type(4))) _Float16 f16x4;
typedef __attribute__((ext_vector_type(4))) float f32x4;

// Workspace layout (float offsets). All activations f16.
#define O_OUT1 0u                       // out1h [b][h][w8][ci] f16 (33.5 MB); gi2 aliases after conv2
#define O_GI   0u                       // gi2 [bblk][s][g][4] f16, 12 MB
#define O_OUT2 16777216u                // out2h [b][h][w2][ci] f16 (8.4 MB)
#define O_OUT3 20971520u                // hsave f16 [s][b][c] (feats no longer materialized)
#define O_W2P  23068672u                // packed fp16 conv2 weights, 1638400 halves
#define O_W3P  24707072u                // packed fp16 conv3 weights, 983040 halves (+ wclsp 4096 halves)
#define O_WIHP 26345472u                // packed fp16 wih, 196608 halves
#define O_WHHP 26443776u                // packed fp16 whh, 196608 halves
// total 26542080 floats = 106.2 MB

__device__ __forceinline__ float sigm_fast(float x) {
    return __builtin_amdgcn_rcpf(1.f + __expf(-x));
}
__device__ __forceinline__ float tanh_fast(float x) {
    return 1.f - 2.f * __builtin_amdgcn_rcpf(1.f + __expf(2.f * x));
}

// select element q (0..3) of a f32x4 with compile-time lanes only (rule #20)
__device__ __forceinline__ float sel4(f32x4 v, int q1, int q2) {
    float lo = q1 ? v[1] : v[0];
    float hi = q1 ? v[3] : v[2];
    return q2 ? hi : lo;
}

// ---------------- pack helper (proven) ----------------
__device__ __forceinline__ void pack768(const float* __restrict__ src, f16* __restrict__ dst, int e) {
    int lane = e & 63;
    int r1 = e >> 6;                            // 0..383
    int tile = r1 % 48, kf = r1 / 48;
    int g = tile * 16 + (lane & 15);
    int k0 = kf * 32 + (lane >> 4) * 8;
    f16x8 v;
#pragma unroll
    for (int j = 0; j < 8; ++j)
        v[j] = (f16)src[(size_t)g * HH + k0 + j];
    *(f16x8*)(dst + (size_t)e * 8) = v;
}

// ---------------- MERGED conv1 + weight prep (proven R6) ----------------
__global__ __launch_bounds__(256) void conv1_pack_kernel(
    const float* __restrict__ x, const float* __restrict__ w1,
    const float* __restrict__ b1, const float* __restrict__ g1,
    const float* __restrict__ bt1, const float* __restrict__ m1,
    const float* __restrict__ v1, f16* __restrict__ out1h,
    const float* __restrict__ w2, const float* __restrict__ w3,
    const float* __restrict__ wih, const float* __restrict__ whh,
    const float* __restrict__ wcls,
    f16* __restrict__ w2p, f16* __restrict__ w3p, f16* __restrict__ wihp,
    f16* __restrict__ whhp, f16* __restrict__ wclsp) {
    __shared__ float xs[5][44];
    int bid = blockIdx.x;
    int tid = threadIdx.x;

    if (bid >= 8192) {                          // ---- pack branch ----
        int blk = bid - 8192;
        if (blk < 800) {                        // conv2 weights (25 taps)
            int e = blk * 256 + tid;
            int lane = e & 63;
            int r1 = e >> 6;
            int ntile = r1 & 15;
            int r2 = r1 >> 4;
            int cs4 = r2 & 3;
            int r3 = r2 >> 2;
            int cs = r3 & 1;
            int tap = r3 >> 1;
            int co = ntile * 16 + (lane & 15);
            int ci0 = cs * 128 + cs4 * 32 + (lane >> 4) * 8;
            f16x8 v;
#pragma unroll
            for (int j = 0; j < 8; ++j)
                v[j] = (f16)w2[(size_t)co * 6400 + (ci0 + j) * 25 + tap];
            *(f16x8*)(w2p + (size_t)e * 8) = v;
        } else if (blk < 1280) {                // conv3 weights (15 taps, kw in {1,2,3})
            int e = (blk - 800) * 256 + tid;
            int lane = e & 63;
            int r1 = e >> 6;
            int ntile = r1 & 15;
            int r2 = r1 >> 4;
            int cs4 = r2 & 3;
            int r3 = r2 >> 2;
            int cs = r3 & 1;
            int tap = r3 >> 1;
            int kh = tap / 3, kw = tap % 3 + 1;
            int co = ntile * 16 + (lane & 15);
            int ci0 = cs * 128 + cs4 * 32 + (lane >> 4) * 8;
            f16x8 v;
#pragma unroll
            for (int j = 0; j < 8; ++j)
                v[j] = (f16)w3[(size_t)co * 6400 + (ci0 + j) * 25 + kh * 5 + kw];
            *(f16x8*)(w3p + (size_t)e * 8) = v;
        } else if (blk < 1376) {
            pack768(wih, wihp, (blk - 1280) * 256 + tid);
        } else if (blk < 1472) {
            pack768(whh, whhp, (blk - 1376) * 256 + tid);
        } else {                                // wcls: 512 entries
#pragma unroll
            for (int i = 0; i < 2; ++i) {
                int e = tid + i * 256;
                int lane = e & 63, kf = e >> 6;
                int nb = lane & 15;
                int c0 = kf * 32 + (lane >> 4) * 8;
                f16x8 v;
#pragma unroll
                for (int j = 0; j < 8; ++j)
                    v[j] = (f16)wcls[nb * HH + c0 + j];
                *(f16x8*)(wclsp + (size_t)e * 8) = v;
            }
        }
        return;
    }

    // ---- conv1 branch (proven body, b/h from 1D bid) ----
    int b = bid >> 9;            // 16
    int h = bid & 511;           // 512
    int c = tid;                 // 256
    int t = tid;
    if (t < 220) {
        int rr = t / 44, cc = t % 44;
        int hh = h + rr - 2, ww = cc - 2;
        float v = 0.f;
        if (hh >= 0 && hh < TT && ww >= 0 && ww < FF) v = x[(b * TT + hh) * FF + ww];
        xs[rr][cc] = v;
    }
    __syncthreads();
    float wr[25];
#pragma unroll
    for (int i = 0; i < 25; ++i) wr[i] = w1[c * 25 + i];
    float sc = g1[c] * rsqrtf(v1[c] + 1e-5f);
    float sh = (b1[c] - m1[c]) * sc + bt1[c];
    float conv[40];
#pragma unroll
    for (int w = 0; w < 40; ++w) conv[w] = 0.f;
#pragma unroll
    for (int kh = 0; kh < 5; ++kh) {
        float rr[44];
#pragma unroll
        for (int i = 0; i < 44; ++i) rr[i] = xs[kh][i];
#pragma unroll
        for (int kw = 0; kw < 5; ++kw) {
            float wv = wr[kh * 5 + kw];
#pragma unroll
            for (int w = 0; w < 40; ++w) conv[w] += rr[w + kw] * wv;
        }
    }
    f16* op = out1h + ((size_t)(b * TT + h) * 8) * CC + c;
#pragma unroll
    for (int j = 0; j < 8; ++j) {
        float m = 0.f;   // relu folded into pool
#pragma unroll
        for (int p = 0; p < 5; ++p) m = fmaxf(m, conv[j * 5 + p] * sc + sh);
        op[j * CC] = (f16)m;
    }
}

// ---------------- conv block 2: fp16 MFMA implicit GEMM + T14 cs=1 reg-prefetch (R6 best) ----------------
__global__ __launch_bounds__(256) void conv2_mfma_kernel(
    const f16* __restrict__ in, const f16* __restrict__ w2p,
    const float* __restrict__ b2, const float* __restrict__ g2,
    const float* __restrict__ bt2, const float* __restrict__ m2,
    const float* __restrict__ v2, f16* __restrict__ out2h) {
    int htile = blockIdx.x;                 // 64
    int b = blockIdx.y;                     // 16
    int h0 = htile * 8;
    int t = threadIdx.x;
    int lane = t & 63, wid = t >> 6;
    int m16 = lane & 15, kq = lane >> 4;

    __shared__ f16 lds_a[12 * 12 * 136];    // 39168 B

#pragma unroll
    for (int i = 0; i < 39; ++i) {
        int idx = t + i * 256;
        if (idx < 9792) ((unsigned*)lds_a)[idx] = 0u;
    }
    __syncthreads();

    f32x4 acc[4][4];
#pragma unroll
    for (int mf = 0; mf < 4; ++mf)
#pragma unroll
        for (int nf = 0; nf < 4; ++nf) acc[mf][nf] = (f32x4)(0.f);

    // stage cs=0 directly to LDS (as proven)
#pragma unroll
    for (int i = 0; i < 6; ++i) {
        int q = t + i * 256;
        int row = q >> 7, rem = q & 127;
        int w = rem >> 4, ci8 = (rem & 15) * 8;
        int hp = h0 - 2 + row;
        f16x8 v = (f16x8)((f16)0.f);
        if (hp >= 0 && hp < TT)
            v = *(const f16x8*)&in[((size_t)(b * TT + hp) * 8 + w) * CC + ci8];
        *(f16x8*)&lds_a[row * 1632 + (w + 2) * 136 + ci8] = v;
    }
    __syncthreads();

    // T14: issue cs=1 loads NOW; vmcnt drain happens at the LDS-write below,
    // after the cs=0 MFMA phase has covered the latency.
    f16x8 pre[6];
#pragma unroll
    for (int i = 0; i < 6; ++i) {
        int q = t + i * 256;
        int row = q >> 7, rem = q & 127;
        int w = rem >> 4, ci8 = (rem & 15) * 8;
        int hp = h0 - 2 + row;
        pre[i] = (f16x8)((f16)0.f);
        if (hp >= 0 && hp < TT)
            pre[i] = *(const f16x8*)&in[((size_t)(b * TT + hp) * 8 + w) * CC + 128 + ci8];
    }

#define CONV2_MFMA_PHASE(CS)                                                                        \
    for (int kh = 0; kh < 5; ++kh) {                                                                \
        _Pragma("unroll")                                                                           \
        for (int kw = 0; kw < 5; ++kw) {                                                            \
            int tap = kh * 5 + kw;                                                                  \
            _Pragma("unroll")                                                                       \
            for (int cs4 = 0; cs4 < 4; ++cs4) {                                                     \
                f16x8 af[4];                                                                        \
                _Pragma("unroll")                                                                   \
                for (int mf = 0; mf < 4; ++mf) {                                                    \
                    int m = mf * 16 + m16;                                                          \
                    int row = (m >> 3) + kh;                                                        \
                    int wp = (m & 7) + kw;                                                          \
                    af[mf] = *(const f16x8*)&lds_a[row * 1632 + wp * 136 + cs4 * 32 + kq * 8];      \
                }                                                                                   \
                const f16x8* bp = (const f16x8*)w2p                                                 \
                    + ((size_t)(((tap * 2 + (CS)) * 4 + cs4) * 16 + wid * 4) * 64 + lane);          \
                _Pragma("unroll")                                                                   \
                for (int nf = 0; nf < 4; ++nf) {                                                    \
                    f16x8 bf = bp[nf * 64];                                                         \
                    _Pragma("unroll")                                                               \
                    for (int mf = 0; mf < 4; ++mf)                                                  \
                        acc[mf][nf] = __builtin_amdgcn_mfma_f32_16x16x32_f16(af[mf], bf,            \
                                                                             acc[mf][nf], 0, 0, 0); \
                }                                                                                   \
            }                                                                                       \
        }                                                                                           \
    }

    CONV2_MFMA_PHASE(0)
    __syncthreads();
    // write prefetched cs=1 tile to LDS (same cells as cs=0; halo untouched)
#pragma unroll
    for (int i = 0; i < 6; ++i) {
        int q = t + i * 256;
        int row = q >> 7, rem = q & 127;
        int w = rem >> 4, ci8 = (rem & 15) * 8;
        *(f16x8*)&lds_a[row * 1632 + (w + 2) * 136 + ci8] = pre[i];
    }
    __syncthreads();
    CONV2_MFMA_PHASE(1)
#undef CONV2_MFMA_PHASE

#pragma unroll
    for (int nf = 0; nf < 4; ++nf) {
        int co = wid * 64 + nf * 16 + m16;
        float sc = g2[co] * rsqrtf(v2[co] + 1e-5f);
        float sh = (b2[co] - m2[co]) * sc + bt2[co];
#pragma unroll
        for (int mf = 0; mf < 4; ++mf) {
            f32x4 v = acc[mf][nf];
            float p = 0.f;
            p = fmaxf(p, v[0] * sc + sh);
            p = fmaxf(p, v[1] * sc + sh);
            p = fmaxf(p, v[2] * sc + sh);
            p = fmaxf(p, v[3] * sc + sh);
            int dh = mf * 2 + (kq >> 1);
            int wout = kq & 1;
            out2h[((size_t)(b * TT + h0 + dh) * 2 + wout) * CC + co] = (f16)p;
        }
    }
}

// ---------------- FUSED conv3 + gi (proven), gi2 written as [b>>2][s][g][b&3] ----------------
__global__ __launch_bounds__(256) void conv3gi_kernel(
    const f16* __restrict__ in, const f16* __restrict__ w3p,
    const float* __restrict__ b3, const float* __restrict__ g3,
    const float* __restrict__ bt3, const float* __restrict__ m3,
    const float* __restrict__ v3, const f16* __restrict__ wihp,
    const float* __restrict__ bih, f16* __restrict__ gi2) {
    int htile = blockIdx.x;                 // 32
    int b = blockIdx.y;                     // 16
    int h0 = htile * 16;
    int t = threadIdx.x;
    int lane = t & 63, wid = t >> 6;
    int m16 = lane & 15, quad = lane >> 4;
    int rb = m16 >> 1, wv = m16 & 1;

    __shared__ f16 lds_a[20 * 6 * 136];     // 32640 B
    __shared__ f16 feats_s[16 * 264];       // 8448 B: pooled feats tile [m][c]

    for (int i = t; i < 8160; i += 256) ((unsigned*)lds_a)[i] = 0u;
    __syncthreads();

    f32x4 acc[2][4];
#pragma unroll
    for (int mf = 0; mf < 2; ++mf)
#pragma unroll
        for (int nf = 0; nf < 4; ++nf) acc[mf][nf] = (f32x4)(0.f);

    for (int cs = 0; cs < 2; ++cs) {
        if (cs) __syncthreads();
#pragma unroll
        for (int i = 0; i < 3; ++i) {
            int q = t + i * 256;
            if (q < 640) {
                int row = q >> 5, rem = q & 31;
                int w = rem >> 4, ci8 = (rem & 15) * 8;
                int hp = h0 - 2 + row;
                f16x8 v = (f16x8)((f16)0.f);
                if (hp >= 0 && hp < TT)
                    v = *(const f16x8*)&in[((size_t)(b * TT + hp) * 2 + w) * CC + cs * 128 + ci8];
                *(f16x8*)&lds_a[row * 816 + (w + 2) * 136 + ci8] = v;
            }
        }
        __syncthreads();
        for (int kh = 0; kh < 5; ++kh) {
#pragma unroll
            for (int kw3 = 0; kw3 < 3; ++kw3) {
                int tap = kh * 3 + kw3;
#pragma unroll
                for (int cs4 = 0; cs4 < 4; ++cs4) {
                    f16x8 af[2];
#pragma unroll
                    for (int mf = 0; mf < 2; ++mf) {
                        int row = mf * 8 + rb + kh;
                        int wp = wv + kw3 + 1;
                        af[mf] = *(const f16x8*)&lds_a[row * 816 + wp * 136 + cs4 * 32 + quad * 8];
                    }
                    const f16x8* bp = (const f16x8*)w3p
                        + ((size_t)(((tap * 2 + cs) * 4 + cs4) * 16 + wid * 4) * 64 + lane);
#pragma unroll
                    for (int nf = 0; nf < 4; ++nf) {
                        f16x8 bf = bp[nf * 64];
#pragma unroll
                        for (int mf = 0; mf < 2; ++mf)
                            acc[mf][nf] = __builtin_amdgcn_mfma_f32_16x16x32_f16(af[mf], bf, acc[mf][nf], 0, 0, 0);
                    }
                }
            }
        }
    }

    // conv3 epilogue -> feats tile in LDS (m = h - h0, c = co)
#pragma unroll
    for (int nf = 0; nf < 4; ++nf) {
        int co = wid * 64 + nf * 16 + m16;
        float sc = g3[co] * rsqrtf(v3[co] + 1e-5f);
        float sh = (b3[co] - m3[co]) * sc + bt3[co];
#pragma unroll
        for (int mf = 0; mf < 2; ++mf) {
            f32x4 v = acc[mf][nf];
            float p0 = fmaxf(0.f, fmaxf(v[0], v[1]) * sc + sh);
            p0 = fmaxf(p0, fmaxf(0.f, fminf(v[0], v[1]) * sc + sh));
            float p1 = fmaxf(0.f, fmaxf(v[2], v[3]) * sc + sh);
            p1 = fmaxf(p1, fmaxf(0.f, fminf(v[2], v[3]) * sc + sh));
            int m = mf * 8 + quad * 2;
            feats_s[m * 264 + co] = (f16)p0;
            feats_s[(m + 1) * 264 + co] = (f16)p1;
        }
    }
    __syncthreads();

    // gi phase: A from feats_s, B = wihp; wave wid covers 12 n-tiles
    f32x4 gacc[12];
#pragma unroll
    for (int i = 0; i < 12; ++i) gacc[i] = (f32x4)(0.f);
#pragma unroll
    for (int kf = 0; kf < 8; ++kf) {
        f16x8 af = *(const f16x8*)&feats_s[m16 * 264 + kf * 32 + quad * 8];
#pragma unroll
        for (int nt = 0; nt < 12; ++nt) {
            f16x8 bf = ((const f16x8*)wihp)[(size_t)(kf * 48 + wid * 12 + nt) * 64 + lane];
            gacc[nt] = __builtin_amdgcn_mfma_f32_16x16x32_f16(af, bf, gacc[nt], 0, 0, 0);
        }
    }
#pragma unroll
    for (int nt = 0; nt < 12; ++nt) {
        int g = (wid * 12 + nt) * 16 + m16;
        float bv = bih[g];
#pragma unroll
        for (int r = 0; r < 4; ++r) {
            int s = h0 + quad * 4 + r;          // s0 = htile*16
            // layout [bblk = b>>2][s][g][bloc = b&3]: each GRU block reads a dense
            // 6 KB/step slice.
            gi2[((((size_t)(b >> 2) * TT + s) * GG + g) << 2) + (b & 3)] = (f16)(gacc[nt][r] + bv);
        }
    }
}

// ---------------- GRU scan (EXACT R3 loop, pinned) + merged classifier tail ----------------
// Scan loop: DO NOT PERTURB (R4/R5 both regressed with identical pipe-busy).
// NEW: classifier merged as a post-loop tail. Each block owns batches
// 4*blk..4*blk+3 and wrote exactly that quarter of hsave, so after
// vmcnt(0)+barrier each wave computes 8 mixed (4s x 4b) 16-row tiles with the
// IDENTICAL fragment layout / kf order / B operand as the proven cls kernel ->
// per-output bit-identical; saves one kernel launch + gap, work hides on the
// 4 scan CUs.
__global__ __launch_bounds__(1024) void gru_mfma_kernel(
    const f16* __restrict__ gi2, const f16* __restrict__ whhp,
    const float* __restrict__ bhh, f16* __restrict__ hsave,
    const f16* __restrict__ wclsp, const float* __restrict__ bcls,
    float* __restrict__ out) {
    int blk = blockIdx.x;                 // batch group: global batches 4*blk .. 4*blk+3
    int t = threadIdx.x;
    int w = t >> 6, lane = t & 63;        // w = 0..15
    int n16 = lane & 15, quad = lane >> 4;
    int r2 = n16 & 3;                     // aliased A-row for this lane
    int q1 = quad & 1, q2 = quad >> 1;    // select bits for acc[g][quad]
    __shared__ f16 hA[2][4 * 272];        // [parity][row=batch 0..3][k], stride 272

    for (int i = t; i < 1088; i += 1024) ((unsigned*)hA)[i] = 0u;

    // preload + PIN 3 weight tiles (96 regs, lands in unified VGPR/AGPR file)
    f16x8 wfrag[8][3];
#pragma unroll
    for (int kf = 0; kf < 8; ++kf)
#pragma unroll
        for (int g = 0; g < 3; ++g)
            wfrag[kf][g] = ((const f16x8*)whhp)[(size_t)(kf * 48 + g * 16 + w) * 64 + lane];
#pragma unroll
    for (int kf = 0; kf < 8; ++kf)
#pragma unroll
        for (int g = 0; g < 3; ++g)
            asm volatile("" : "+v"(wfrag[kf][g]));   // opaque: cannot be re-loaded

    int c = w * 16 + n16;
    float bh0 = bhh[c], bh1 = bhh[HH + c], bh2 = bhh[2 * HH + c];
    float hold = 0.f;
    f16 hprev = (f16)0.f;
    int bg = blk * 4 + quad;              // global batch of this thread

    // gi slice for this batch group; per-step stride = GG*4 halves
    const f16* gbase = gi2 + (size_t)blk * ((size_t)TT * GG * 4);
    int go0 = c * 4 + quad;               // gate 0 offset within a step
    int go1 = (c + HH) * 4 + quad;
    int go2 = (c + 2 * HH) * 4 + quad;

    // prefetch step 0
    f16 gc0 = gbase[go0];
    f16 gc1 = gbase[go1];
    f16 gc2 = gbase[go2];
    const f16* gp = gbase + GG * 4;       // prefetch pointer (step s+1)
    __syncthreads();

    for (int s = 0; s < TT; ++s) {
        // preload ALL 8 A-fragments (8x ds_read_b128, staged lgkm waits)
        const f16* hrow = &hA[s & 1][r2 * 272 + quad * 8];
        f16x8 af[8];
#pragma unroll
        for (int kf = 0; kf < 8; ++kf)
            af[kf] = *(const f16x8*)(hrow + kf * 32);

        // vmem work issued inside the MFMA window (fire-and-forget):
        // gi prefetch for step s+1 (at s=TT-1 reads 6 KB past gi2 -- still
        // inside the dead out1h alias region, values unused)
        f16 gn0 = gp[go0];
        f16 gn1 = gp[go1];
        f16 gn2 = gp[go2];
        gp += GG * 4;
        // deferred hsave store for step s-1
        if (s > 0)
            hsave[((size_t)(s - 1) * 16 + bg) * HH + c] = hprev;

        // hoisted gi+bias (left-assoc identical to (gi + bh) + a)
        float x0 = (float)gc0 + bh0;
        float x1 = (float)gc1 + bh1;
        float x2 = (float)gc2;

        f32x4 acc[3];
#pragma unroll
        for (int g = 0; g < 3; ++g) acc[g] = (f32x4)(0.f);
#pragma unroll
        for (int kf = 0; kf < 8; ++kf) {
#pragma unroll
            for (int g = 0; g < 3; ++g)
                acc[g] = __builtin_amdgcn_mfma_f32_16x16x32_f16(af[kf], wfrag[kf][g], acc[g], 0, 0, 0);
        }

        // register select: acc[g] reg r = gh[batch r][gate g][channel c]
        float a0 = sel4(acc[0], q1, q2);
        float a1 = sel4(acc[1], q1, q2);
        float a2 = sel4(acc[2], q1, q2);

        // gate math for this thread's (b=quad, c) pair -- identical math
        float rr = sigm_fast(x0 + a0);
        float zz = sigm_fast(x1 + a1);
        float nn = tanh_fast(x2 + rr * (bh2 + a2));
        hold = nn + zz * (hold - nn);
        f16 hv = (f16)hold;
        hprev = hv;
        hA[(s + 1) & 1][quad * 272 + c] = hv;   // row = batch = quad
        gc0 = gn0; gc1 = gn1; gc2 = gn2;
        // raw barrier: LDS-only drain, no vmcnt(0)
        asm volatile("s_waitcnt lgkmcnt(0)\n\ts_barrier" ::: "memory");
    }
    // final hsave store (step TT-1)
    hsave[((size_t)(TT - 1) * 16 + bg) * HH + c] = hprev;

    // ---- merged classifier tail: this block's 4 batches, all 512 steps ----
    // All hsave stores for batches 4*blk..4*blk+3 were issued by THIS block;
    // drain + barrier makes them visible to all its waves.
    asm volatile("s_waitcnt vmcnt(0)" ::: "memory");
    __syncthreads();
    {
        float bc = bcls[n16];
        f16x8 cbf[8];
#pragma unroll
        for (int kf = 0; kf < 8; ++kf)
            cbf[kf] = ((const f16x8*)wclsp)[kf * 64 + lane];
        // A-row n16 -> (s = s0 + (n16>>2), b = blk*4 + (n16&3)); same fragment
        // pattern (k = kf*32 + quad*8) and kf order as the proven cls kernel.
        int arow_s = n16 >> 2, arow_b = blk * 4 + (n16 & 3);
        for (int ti = 0; ti < 8; ++ti) {
            int s0 = w * 32 + ti * 4;           // wave w covers s in [w*32, w*32+32)
            f32x4 ac = (f32x4)(0.f);
#pragma unroll
            for (int kf = 0; kf < 8; ++kf) {
                f16x8 afc = *(const f16x8*)&hsave[((size_t)(s0 + arow_s) * 16 + arow_b) * HH
                                                  + kf * 32 + quad * 8];
                ac = __builtin_amdgcn_mfma_f32_16x16x32_f16(afc, cbf[kf], ac, 0, 0, 0);
            }
#pragma unroll
            for (int r = 0; r < 4; ++r) {
                int i = quad * 4 + r;           // D-row = A-row index i
                int bo = blk * 4 + (i & 3);
                int so = s0 + (i >> 2);
                out[((size_t)bo * TT + so) * NB + n16] = ac[r] + bc;
            }
        }
    }
}

extern "C" void kernel_launch(void* const* d_in, const int* in_sizes, int n_in,
                              void* d_out, int out_size, void* d_ws, size_t ws_size,
                              hipStream_t stream) {
    const float* x    = (const float*)d_in[0];
    const float* w1   = (const float*)d_in[1];
    const float* b1   = (const float*)d_in[2];
    const float* g1   = (const float*)d_in[3];
    const float* bt1  = (const float*)d_in[4];
    const float* m1   = (const float*)d_in[5];
    const float* v1   = (const float*)d_in[6];
    const float* w2   = (const float*)d_in[7];
    const float* b2   = (const float*)d_in[8];
    const float* g2   = (const float*)d_in[9];
    const float* bt2  = (const float*)d_in[10];
    const float* m2   = (const float*)d_in[11];
    const float* v2   = (const float*)d_in[12];
    const float* w3   = (const float*)d_in[13];
    const float* b3   = (const float*)d_in[14];
    const float* g3   = (const float*)d_in[15];
    const float* bt3  = (const float*)d_in[16];
    const float* m3   = (const float*)d_in[17];
    const float* v3   = (const float*)d_in[18];
    const float* wih  = (const float*)d_in[19];
    const float* whh  = (const float*)d_in[20];
    const float* bih  = (const float*)d_in[21];
    const float* bhh  = (const float*)d_in[22];
    const float* wcls = (const float*)d_in[23];
    const float* bcls = (const float*)d_in[24];

    float* ws    = (float*)d_ws;
    f16*   out1h = (f16*)(ws + O_OUT1);
    f16*   out2h = (f16*)(ws + O_OUT2);
    f16*   gi2   = (f16*)(ws + O_GI);      // aliases out1h (dead after conv2)
    f16*   w2p   = (f16*)(ws + O_W2P);
    f16*   w3p   = (f16*)(ws + O_W3P);
    f16*   wclsp = (f16*)(ws + O_W3P) + 983040;
    f16*   wihp  = (f16*)(ws + O_WIHP);
    f16*   whhp  = (f16*)(ws + O_WHHP);
    f16*   hsave = (f16*)(ws + O_OUT3);
    float* fout  = (float*)d_out;

    // merged conv1 + all weight prep (blocks 0..8191 conv1, 8192..9664 pack)
    conv1_pack_kernel<<<9665, 256, 0, stream>>>(x, w1, b1, g1, bt1, m1, v1, out1h,
                                                w2, w3, wih, whh, wcls,
                                                w2p, w3p, wihp, whhp, wclsp);

    // conv2: proven M=64 + T14 cs=1 register prefetch (R6 best config)
    conv2_mfma_kernel<<<dim3(64, 16), 256, 0, stream>>>(out1h, w2p, b2, g2, bt2, m2, v2, out2h);

    // fused conv3 + gi: feats never materialized; writes gi2 [bblk][s][g][4] directly
    conv3gi_kernel<<<dim3(32, 16), 256, 0, stream>>>(out2h, w3p, b3, g3, bt3, m3, v3,
                                                     wihp, bih, gi2);

    // GRU scan (pinned R3 loop) + merged classifier tail -> writes fout directly
    gru_mfma_kernel<<<4, 1024, 0, stream>>>(gi2, whhp, bhh, hsave, wclsp, bcls, fout);
}

// Round 9
// 1161.773 us; speedup vs baseline: 1.2213x; 1.2213x over previous
//
#include <hip/hip_runtime.h>
#include <hip/hip_bf16.h>
#include <math.h>

// Problem constants
#define BB 16
#define TT 512
#define FF 40
#define CC 256
#define HH 256
#define GG 768   // 3*H
#define NB 16

typedef _Float16 f16;
typedef __attribute__((ext_vector_type(8))) _Float16 f16x8;
typedef __attribute__((ext_vector_type(4))) _Float16 f16x4;
typedef __attribute__((ext_vector_type(4))) float f32x4;

// Workspace layout (float offsets). All activations f16.
#define O_OUT1 0u                       // out1h [b][h][w8][ci] f16 (33.5 MB); gi2 aliases after conv2
#define O_GI   0u                       // gi2 [bblk][s][g][4] f16, 12 MB
#define O_OUT2 16777216u                // out2h [b][h][w2][ci] f16 (8.4 MB)
#define O_OUT3 20971520u                // hsave f16 [s][b][c] (feats no longer materialized)
#define O_W2P  23068672u                // packed fp16 conv2 weights, 1638400 halves
#define O_W3P  24707072u                // packed fp16 conv3 weights, 983040 halves (+ wclsp 4096 halves)
#define O_WIHP 26345472u                // packed fp16 wih, 196608 halves
#define O_WHHP 26443776u                // packed fp16 whh, 196608 halves
// total 26542080 floats = 106.2 MB

__device__ __forceinline__ float sigm_fast(float x) {
    return __builtin_amdgcn_rcpf(1.f + __expf(-x));
}
__device__ __forceinline__ float tanh_fast(float x) {
    return 1.f - 2.f * __builtin_amdgcn_rcpf(1.f + __expf(2.f * x));
}

// select element q (0..3) of a f32x4 with compile-time lanes only (rule #20)
__device__ __forceinline__ float sel4(f32x4 v, int q1, int q2) {
    float lo = q1 ? v[1] : v[0];
    float hi = q1 ? v[3] : v[2];
    return q2 ? hi : lo;
}

// ---------------- pack helper (proven) ----------------
__device__ __forceinline__ void pack768(const float* __restrict__ src, f16* __restrict__ dst, int e) {
    int lane = e & 63;
    int r1 = e >> 6;                            // 0..383
    int tile = r1 % 48, kf = r1 / 48;
    int g = tile * 16 + (lane & 15);
    int k0 = kf * 32 + (lane >> 4) * 8;
    f16x8 v;
#pragma unroll
    for (int j = 0; j < 8; ++j)
        v[j] = (f16)src[(size_t)g * HH + k0 + j];
    *(f16x8*)(dst + (size_t)e * 8) = v;
}

// ---------------- MERGED conv1 + weight prep (proven R6) ----------------
__global__ __launch_bounds__(256) void conv1_pack_kernel(
    const float* __restrict__ x, const float* __restrict__ w1,
    const float* __restrict__ b1, const float* __restrict__ g1,
    const float* __restrict__ bt1, const float* __restrict__ m1,
    const float* __restrict__ v1, f16* __restrict__ out1h,
    const float* __restrict__ w2, const float* __restrict__ w3,
    const float* __restrict__ wih, const float* __restrict__ whh,
    const float* __restrict__ wcls,
    f16* __restrict__ w2p, f16* __restrict__ w3p, f16* __restrict__ wihp,
    f16* __restrict__ whhp, f16* __restrict__ wclsp) {
    __shared__ float xs[5][44];
    int bid = blockIdx.x;
    int tid = threadIdx.x;

    if (bid >= 8192) {                          // ---- pack branch ----
        int blk = bid - 8192;
        if (blk < 800) {                        // conv2 weights (25 taps)
            int e = blk * 256 + tid;
            int lane = e & 63;
            int r1 = e >> 6;
            int ntile = r1 & 15;
            int r2 = r1 >> 4;
            int cs4 = r2 & 3;
            int r3 = r2 >> 2;
            int cs = r3 & 1;
            int tap = r3 >> 1;
            int co = ntile * 16 + (lane & 15);
            int ci0 = cs * 128 + cs4 * 32 + (lane >> 4) * 8;
            f16x8 v;
#pragma unroll
            for (int j = 0; j < 8; ++j)
                v[j] = (f16)w2[(size_t)co * 6400 + (ci0 + j) * 25 + tap];
            *(f16x8*)(w2p + (size_t)e * 8) = v;
        } else if (blk < 1280) {                // conv3 weights (15 taps, kw in {1,2,3})
            int e = (blk - 800) * 256 + tid;
            int lane = e & 63;
            int r1 = e >> 6;
            int ntile = r1 & 15;
            int r2 = r1 >> 4;
            int cs4 = r2 & 3;
            int r3 = r2 >> 2;
            int cs = r3 & 1;
            int tap = r3 >> 1;
            int kh = tap / 3, kw = tap % 3 + 1;
            int co = ntile * 16 + (lane & 15);
            int ci0 = cs * 128 + cs4 * 32 + (lane >> 4) * 8;
            f16x8 v;
#pragma unroll
            for (int j = 0; j < 8; ++j)
                v[j] = (f16)w3[(size_t)co * 6400 + (ci0 + j) * 25 + kh * 5 + kw];
            *(f16x8*)(w3p + (size_t)e * 8) = v;
        } else if (blk < 1376) {
            pack768(wih, wihp, (blk - 1280) * 256 + tid);
        } else if (blk < 1472) {
            pack768(whh, whhp, (blk - 1376) * 256 + tid);
        } else {                                // wcls: 512 entries
#pragma unroll
            for (int i = 0; i < 2; ++i) {
                int e = tid + i * 256;
                int lane = e & 63, kf = e >> 6;
                int nb = lane & 15;
                int c0 = kf * 32 + (lane >> 4) * 8;
                f16x8 v;
#pragma unroll
                for (int j = 0; j < 8; ++j)
                    v[j] = (f16)wcls[nb * HH + c0 + j];
                *(f16x8*)(wclsp + (size_t)e * 8) = v;
            }
        }
        return;
    }

    // ---- conv1 branch (proven body, b/h from 1D bid) ----
    int b = bid >> 9;            // 16
    int h = bid & 511;           // 512
    int c = tid;                 // 256
    int t = tid;
    if (t < 220) {
        int rr = t / 44, cc = t % 44;
        int hh = h + rr - 2, ww = cc - 2;
        float v = 0.f;
        if (hh >= 0 && hh < TT && ww >= 0 && ww < FF) v = x[(b * TT + hh) * FF + ww];
        xs[rr][cc] = v;
    }
    __syncthreads();
    float wr[25];
#pragma unroll
    for (int i = 0; i < 25; ++i) wr[i] = w1[c * 25 + i];
    float sc = g1[c] * rsqrtf(v1[c] + 1e-5f);
    float sh = (b1[c] - m1[c]) * sc + bt1[c];
    float conv[40];
#pragma unroll
    for (int w = 0; w < 40; ++w) conv[w] = 0.f;
#pragma unroll
    for (int kh = 0; kh < 5; ++kh) {
        float rr[44];
#pragma unroll
        for (int i = 0; i < 44; ++i) rr[i] = xs[kh][i];
#pragma unroll
        for (int kw = 0; kw < 5; ++kw) {
            float wv = wr[kh * 5 + kw];
#pragma unroll
            for (int w = 0; w < 40; ++w) conv[w] += rr[w + kw] * wv;
        }
    }
    f16* op = out1h + ((size_t)(b * TT + h) * 8) * CC + c;
#pragma unroll
    for (int j = 0; j < 8; ++j) {
        float m = 0.f;   // relu folded into pool
#pragma unroll
        for (int p = 0; p < 5; ++p) m = fmaxf(m, conv[j * 5 + p] * sc + sh);
        op[j * CC] = (f16)m;
    }
}

// ---------------- conv block 2: fp16 MFMA implicit GEMM + T14 cs=1 reg-prefetch (R6 best) ----------------
__global__ __launch_bounds__(256) void conv2_mfma_kernel(
    const f16* __restrict__ in, const f16* __restrict__ w2p,
    const float* __restrict__ b2, const float* __restrict__ g2,
    const float* __restrict__ bt2, const float* __restrict__ m2,
    const float* __restrict__ v2, f16* __restrict__ out2h) {
    int htile = blockIdx.x;                 // 64
    int b = blockIdx.y;                     // 16
    int h0 = htile * 8;
    int t = threadIdx.x;
    int lane = t & 63, wid = t >> 6;
    int m16 = lane & 15, kq = lane >> 4;

    __shared__ f16 lds_a[12 * 12 * 136];    // 39168 B

#pragma unroll
    for (int i = 0; i < 39; ++i) {
        int idx = t + i * 256;
        if (idx < 9792) ((unsigned*)lds_a)[idx] = 0u;
    }
    __syncthreads();

    f32x4 acc[4][4];
#pragma unroll
    for (int mf = 0; mf < 4; ++mf)
#pragma unroll
        for (int nf = 0; nf < 4; ++nf) acc[mf][nf] = (f32x4)(0.f);

    // stage cs=0 directly to LDS (as proven)
#pragma unroll
    for (int i = 0; i < 6; ++i) {
        int q = t + i * 256;
        int row = q >> 7, rem = q & 127;
        int w = rem >> 4, ci8 = (rem & 15) * 8;
        int hp = h0 - 2 + row;
        f16x8 v = (f16x8)((f16)0.f);
        if (hp >= 0 && hp < TT)
            v = *(const f16x8*)&in[((size_t)(b * TT + hp) * 8 + w) * CC + ci8];
        *(f16x8*)&lds_a[row * 1632 + (w + 2) * 136 + ci8] = v;
    }
    __syncthreads();

    // T14: issue cs=1 loads NOW; vmcnt drain happens at the LDS-write below,
    // after the cs=0 MFMA phase has covered the latency.
    f16x8 pre[6];
#pragma unroll
    for (int i = 0; i < 6; ++i) {
        int q = t + i * 256;
        int row = q >> 7, rem = q & 127;
        int w = rem >> 4, ci8 = (rem & 15) * 8;
        int hp = h0 - 2 + row;
        pre[i] = (f16x8)((f16)0.f);
        if (hp >= 0 && hp < TT)
            pre[i] = *(const f16x8*)&in[((size_t)(b * TT + hp) * 8 + w) * CC + 128 + ci8];
    }

#define CONV2_MFMA_PHASE(CS)                                                                        \
    for (int kh = 0; kh < 5; ++kh) {                                                                \
        _Pragma("unroll")                                                                           \
        for (int kw = 0; kw < 5; ++kw) {                                                            \
            int tap = kh * 5 + kw;                                                                  \
            _Pragma("unroll")                                                                       \
            for (int cs4 = 0; cs4 < 4; ++cs4) {                                                     \
                f16x8 af[4];                                                                        \
                _Pragma("unroll")                                                                   \
                for (int mf = 0; mf < 4; ++mf) {                                                    \
                    int m = mf * 16 + m16;                                                          \
                    int row = (m >> 3) + kh;                                                        \
                    int wp = (m & 7) + kw;                                                          \
                    af[mf] = *(const f16x8*)&lds_a[row * 1632 + wp * 136 + cs4 * 32 + kq * 8];      \
                }                                                                                   \
                const f16x8* bp = (const f16x8*)w2p                                                 \
                    + ((size_t)(((tap * 2 + (CS)) * 4 + cs4) * 16 + wid * 4) * 64 + lane);          \
                _Pragma("unroll")                                                                   \
                for (int nf = 0; nf < 4; ++nf) {                                                    \
                    f16x8 bf = bp[nf * 64];                                                         \
                    _Pragma("unroll")                                                               \
                    for (int mf = 0; mf < 4; ++mf)                                                  \
                        acc[mf][nf] = __builtin_amdgcn_mfma_f32_16x16x32_f16(af[mf], bf,            \
                                                                             acc[mf][nf], 0, 0, 0); \
                }                                                                                   \
            }                                                                                       \
        }                                                                                           \
    }

    CONV2_MFMA_PHASE(0)
    __syncthreads();
    // write prefetched cs=1 tile to LDS (same cells as cs=0; halo untouched)
#pragma unroll
    for (int i = 0; i < 6; ++i) {
        int q = t + i * 256;
        int row = q >> 7, rem = q & 127;
        int w = rem >> 4, ci8 = (rem & 15) * 8;
        *(f16x8*)&lds_a[row * 1632 + (w + 2) * 136 + ci8] = pre[i];
    }
    __syncthreads();
    CONV2_MFMA_PHASE(1)
#undef CONV2_MFMA_PHASE

#pragma unroll
    for (int nf = 0; nf < 4; ++nf) {
        int co = wid * 64 + nf * 16 + m16;
        float sc = g2[co] * rsqrtf(v2[co] + 1e-5f);
        float sh = (b2[co] - m2[co]) * sc + bt2[co];
#pragma unroll
        for (int mf = 0; mf < 4; ++mf) {
            f32x4 v = acc[mf][nf];
            float p = 0.f;
            p = fmaxf(p, v[0] * sc + sh);
            p = fmaxf(p, v[1] * sc + sh);
            p = fmaxf(p, v[2] * sc + sh);
            p = fmaxf(p, v[3] * sc + sh);
            int dh = mf * 2 + (kq >> 1);
            int wout = kq & 1;
            out2h[((size_t)(b * TT + h0 + dh) * 2 + wout) * CC + co] = (f16)p;
        }
    }
}

// ---------------- FUSED conv3 + gi (proven), gi2 written as [b>>2][s][g][b&3] ----------------
__global__ __launch_bounds__(256) void conv3gi_kernel(
    const f16* __restrict__ in, const f16* __restrict__ w3p,
    const float* __restrict__ b3, const float* __restrict__ g3,
    const float* __restrict__ bt3, const float* __restrict__ m3,
    const float* __restrict__ v3, const f16* __restrict__ wihp,
    const float* __restrict__ bih, f16* __restrict__ gi2) {
    int htile = blockIdx.x;                 // 32
    int b = blockIdx.y;                     // 16
    int h0 = htile * 16;
    int t = threadIdx.x;
    int lane = t & 63, wid = t >> 6;
    int m16 = lane & 15, quad = lane >> 4;
    int rb = m16 >> 1, wv = m16 & 1;

    __shared__ f16 lds_a[20 * 6 * 136];     // 32640 B
    __shared__ f16 feats_s[16 * 264];       // 8448 B: pooled feats tile [m][c]

    for (int i = t; i < 8160; i += 256) ((unsigned*)lds_a)[i] = 0u;
    __syncthreads();

    f32x4 acc[2][4];
#pragma unroll
    for (int mf = 0; mf < 2; ++mf)
#pragma unroll
        for (int nf = 0; nf < 4; ++nf) acc[mf][nf] = (f32x4)(0.f);

    for (int cs = 0; cs < 2; ++cs) {
        if (cs) __syncthreads();
#pragma unroll
        for (int i = 0; i < 3; ++i) {
            int q = t + i * 256;
            if (q < 640) {
                int row = q >> 5, rem = q & 31;
                int w = rem >> 4, ci8 = (rem & 15) * 8;
                int hp = h0 - 2 + row;
                f16x8 v = (f16x8)((f16)0.f);
                if (hp >= 0 && hp < TT)
                    v = *(const f16x8*)&in[((size_t)(b * TT + hp) * 2 + w) * CC + cs * 128 + ci8];
                *(f16x8*)&lds_a[row * 816 + (w + 2) * 136 + ci8] = v;
            }
        }
        __syncthreads();
        for (int kh = 0; kh < 5; ++kh) {
#pragma unroll
            for (int kw3 = 0; kw3 < 3; ++kw3) {
                int tap = kh * 3 + kw3;
#pragma unroll
                for (int cs4 = 0; cs4 < 4; ++cs4) {
                    f16x8 af[2];
#pragma unroll
                    for (int mf = 0; mf < 2; ++mf) {
                        int row = mf * 8 + rb + kh;
                        int wp = wv + kw3 + 1;
                        af[mf] = *(const f16x8*)&lds_a[row * 816 + wp * 136 + cs4 * 32 + quad * 8];
                    }
                    const f16x8* bp = (const f16x8*)w3p
                        + ((size_t)(((tap * 2 + cs) * 4 + cs4) * 16 + wid * 4) * 64 + lane);
#pragma unroll
                    for (int nf = 0; nf < 4; ++nf) {
                        f16x8 bf = bp[nf * 64];
#pragma unroll
                        for (int mf = 0; mf < 2; ++mf)
                            acc[mf][nf] = __builtin_amdgcn_mfma_f32_16x16x32_f16(af[mf], bf, acc[mf][nf], 0, 0, 0);
                    }
                }
            }
        }
    }

    // conv3 epilogue -> feats tile in LDS (m = h - h0, c = co)
#pragma unroll
    for (int nf = 0; nf < 4; ++nf) {
        int co = wid * 64 + nf * 16 + m16;
        float sc = g3[co] * rsqrtf(v3[co] + 1e-5f);
        float sh = (b3[co] - m3[co]) * sc + bt3[co];
#pragma unroll
        for (int mf = 0; mf < 2; ++mf) {
            f32x4 v = acc[mf][nf];
            float p0 = fmaxf(0.f, fmaxf(v[0], v[1]) * sc + sh);
            p0 = fmaxf(p0, fmaxf(0.f, fminf(v[0], v[1]) * sc + sh));
            float p1 = fmaxf(0.f, fmaxf(v[2], v[3]) * sc + sh);
            p1 = fmaxf(p1, fmaxf(0.f, fminf(v[2], v[3]) * sc + sh));
            int m = mf * 8 + quad * 2;
            feats_s[m * 264 + co] = (f16)p0;
            feats_s[(m + 1) * 264 + co] = (f16)p1;
        }
    }
    __syncthreads();

    // gi phase: A from feats_s, B = wihp; wave wid covers 12 n-tiles
    f32x4 gacc[12];
#pragma unroll
    for (int i = 0; i < 12; ++i) gacc[i] = (f32x4)(0.f);
#pragma unroll
    for (int kf = 0; kf < 8; ++kf) {
        f16x8 af = *(const f16x8*)&feats_s[m16 * 264 + kf * 32 + quad * 8];
#pragma unroll
        for (int nt = 0; nt < 12; ++nt) {
            f16x8 bf = ((const f16x8*)wihp)[(size_t)(kf * 48 + wid * 12 + nt) * 64 + lane];
            gacc[nt] = __builtin_amdgcn_mfma_f32_16x16x32_f16(af, bf, gacc[nt], 0, 0, 0);
        }
    }
#pragma unroll
    for (int nt = 0; nt < 12; ++nt) {
        int g = (wid * 12 + nt) * 16 + m16;
        float bv = bih[g];
#pragma unroll
        for (int r = 0; r < 4; ++r) {
            int s = h0 + quad * 4 + r;          // s0 = htile*16
            // layout [bblk = b>>2][s][g][bloc = b&3]: each GRU block reads a dense
            // 6 KB/step slice.
            gi2[((((size_t)(b >> 2) * TT + s) * GG + g) << 2) + (b & 3)] = (f16)(gacc[nt][r] + bv);
        }
    }
}

// ---------------- GRU scan: EXACT R3 source (proven ~652 us) -- DO NOT PERTURB ----------------
// At measured structural floor: per-step MFMA-busy 1862 cyc + VALU-busy 1134
// sums to ~98% of the 3065-cyc step, serialized by the recurrence barrier.
// R4 (ptr ping-pong), R5 (manual unroll-by-2), and R8 (cls tail appended after
// the loop) ALL regressed with pipe-busy cycles conserved -- any source change
// to this kernel, even outside the loop, perturbs the fragile schedule. Pinned.
__global__ __launch_bounds__(1024) void gru_mfma_kernel(
    const f16* __restrict__ gi2, const f16* __restrict__ whhp,
    const float* __restrict__ bhh, f16* __restrict__ hsave) {
    int blk = blockIdx.x;                 // batch group: global batches 4*blk .. 4*blk+3
    int t = threadIdx.x;
    int w = t >> 6, lane = t & 63;        // w = 0..15
    int n16 = lane & 15, quad = lane >> 4;
    int r2 = n16 & 3;                     // aliased A-row for this lane
    int q1 = quad & 1, q2 = quad >> 1;    // select bits for acc[g][quad]
    __shared__ f16 hA[2][4 * 272];        // [parity][row=batch 0..3][k], stride 272

    for (int i = t; i < 1088; i += 1024) ((unsigned*)hA)[i] = 0u;

    // preload + PIN 3 weight tiles (96 regs, lands in unified VGPR/AGPR file)
    f16x8 wfrag[8][3];
#pragma unroll
    for (int kf = 0; kf < 8; ++kf)
#pragma unroll
        for (int g = 0; g < 3; ++g)
            wfrag[kf][g] = ((const f16x8*)whhp)[(size_t)(kf * 48 + g * 16 + w) * 64 + lane];
#pragma unroll
    for (int kf = 0; kf < 8; ++kf)
#pragma unroll
        for (int g = 0; g < 3; ++g)
            asm volatile("" : "+v"(wfrag[kf][g]));   // opaque: cannot be re-loaded

    int c = w * 16 + n16;
    float bh0 = bhh[c], bh1 = bhh[HH + c], bh2 = bhh[2 * HH + c];
    float hold = 0.f;
    f16 hprev = (f16)0.f;
    int bg = blk * 4 + quad;              // global batch of this thread

    // gi slice for this batch group; per-step stride = GG*4 halves
    const f16* gbase = gi2 + (size_t)blk * ((size_t)TT * GG * 4);
    int go0 = c * 4 + quad;               // gate 0 offset within a step
    int go1 = (c + HH) * 4 + quad;
    int go2 = (c + 2 * HH) * 4 + quad;

    // prefetch step 0
    f16 gc0 = gbase[go0];
    f16 gc1 = gbase[go1];
    f16 gc2 = gbase[go2];
    const f16* gp = gbase + GG * 4;       // prefetch pointer (step s+1)
    __syncthreads();

    for (int s = 0; s < TT; ++s) {
        // preload ALL 8 A-fragments (8x ds_read_b128, staged lgkm waits)
        const f16* hrow = &hA[s & 1][r2 * 272 + quad * 8];
        f16x8 af[8];
#pragma unroll
        for (int kf = 0; kf < 8; ++kf)
            af[kf] = *(const f16x8*)(hrow + kf * 32);

        // vmem work issued inside the MFMA window (fire-and-forget):
        // gi prefetch for step s+1 (at s=TT-1 reads 6 KB past gi2 -- still
        // inside the dead out1h alias region, values unused)
        f16 gn0 = gp[go0];
        f16 gn1 = gp[go1];
        f16 gn2 = gp[go2];
        gp += GG * 4;
        // deferred hsave store for step s-1
        if (s > 0)
            hsave[((size_t)(s - 1) * 16 + bg) * HH + c] = hprev;

        // hoisted gi+bias (left-assoc identical to (gi + bh) + a)
        float x0 = (float)gc0 + bh0;
        float x1 = (float)gc1 + bh1;
        float x2 = (float)gc2;

        f32x4 acc[3];
#pragma unroll
        for (int g = 0; g < 3; ++g) acc[g] = (f32x4)(0.f);
#pragma unroll
        for (int kf = 0; kf < 8; ++kf) {
#pragma unroll
            for (int g = 0; g < 3; ++g)
                acc[g] = __builtin_amdgcn_mfma_f32_16x16x32_f16(af[kf], wfrag[kf][g], acc[g], 0, 0, 0);
        }

        // register select: acc[g] reg r = gh[batch r][gate g][channel c]
        float a0 = sel4(acc[0], q1, q2);
        float a1 = sel4(acc[1], q1, q2);
        float a2 = sel4(acc[2], q1, q2);

        // gate math for this thread's (b=quad, c) pair -- identical math
        float rr = sigm_fast(x0 + a0);
        float zz = sigm_fast(x1 + a1);
        float nn = tanh_fast(x2 + rr * (bh2 + a2));
        hold = nn + zz * (hold - nn);
        f16 hv = (f16)hold;
        hprev = hv;
        hA[(s + 1) & 1][quad * 272 + c] = hv;   // row = batch = quad
        gc0 = gn0; gc1 = gn1; gc2 = gn2;
        // raw barrier: LDS-only drain, no vmcnt(0)
        asm volatile("s_waitcnt lgkmcnt(0)\n\ts_barrier" ::: "memory");
    }
    // final hsave store (step TT-1)
    hsave[((size_t)(TT - 1) * 16 + bg) * HH + c] = hprev;
}

// ---------------- classifier: [8192 bt x 256] @ [256 x 16], MFMA (proven) ----------------
__global__ __launch_bounds__(256) void cls_kernel(
    const f16* __restrict__ hsave, const f16* __restrict__ wclsp,
    const float* __restrict__ bcls, float* __restrict__ out) {
    int s = blockIdx.x * 4 + (threadIdx.x >> 6);   // grid 128, one s per wave
    int lane = threadIdx.x & 63;
    int n16 = lane & 15, quad = lane >> 4;
    f32x4 ac = (f32x4)(0.f);
#pragma unroll
    for (int kf = 0; kf < 8; ++kf) {
        f16x8 af = *(const f16x8*)&hsave[((size_t)s * 16 + n16) * 256 + kf * 32 + quad * 8];
        f16x8 bf = ((const f16x8*)wclsp)[kf * 64 + lane];
        ac = __builtin_amdgcn_mfma_f32_16x16x32_f16(af, bf, ac, 0, 0, 0);
    }
    float bc = bcls[n16];
#pragma unroll
    for (int r = 0; r < 4; ++r)
        out[((size_t)(quad * 4 + r) * TT + s) * NB + n16] = ac[r] + bc;
}

extern "C" void kernel_launch(void* const* d_in, const int* in_sizes, int n_in,
                              void* d_out, int out_size, void* d_ws, size_t ws_size,
                              hipStream_t stream) {
    const float* x    = (const float*)d_in[0];
    const float* w1   = (const float*)d_in[1];
    const float* b1   = (const float*)d_in[2];
    const float* g1   = (const float*)d_in[3];
    const float* bt1  = (const float*)d_in[4];
    const float* m1   = (const float*)d_in[5];
    const float* v1   = (const float*)d_in[6];
    const float* w2   = (const float*)d_in[7];
    const float* b2   = (const float*)d_in[8];
    const float* g2   = (const float*)d_in[9];
    const float* bt2  = (const float*)d_in[10];
    const float* m2   = (const float*)d_in[11];
    const float* v2   = (const float*)d_in[12];
    const float* w3   = (const float*)d_in[13];
    const float* b3   = (const float*)d_in[14];
    const float* g3   = (const float*)d_in[15];
    const float* bt3  = (const float*)d_in[16];
    const float* m3   = (const float*)d_in[17];
    const float* v3   = (const float*)d_in[18];
    const float* wih  = (const float*)d_in[19];
    const float* whh  = (const float*)d_in[20];
    const float* bih  = (const float*)d_in[21];
    const float* bhh  = (const float*)d_in[22];
    const float* wcls = (const float*)d_in[23];
    const float* bcls = (const float*)d_in[24];

    float* ws    = (float*)d_ws;
    f16*   out1h = (f16*)(ws + O_OUT1);
    f16*   out2h = (f16*)(ws + O_OUT2);
    f16*   gi2   = (f16*)(ws + O_GI);      // aliases out1h (dead after conv2)
    f16*   w2p   = (f16*)(ws + O_W2P);
    f16*   w3p   = (f16*)(ws + O_W3P);
    f16*   wclsp = (f16*)(ws + O_W3P) + 983040;
    f16*   wihp  = (f16*)(ws + O_WIHP);
    f16*   whhp  = (f16*)(ws + O_WHHP);
    f16*   hsave = (f16*)(ws + O_OUT3);
    float* fout  = (float*)d_out;

    // merged conv1 + all weight prep (blocks 0..8191 conv1, 8192..9664 pack)
    conv1_pack_kernel<<<9665, 256, 0, stream>>>(x, w1, b1, g1, bt1, m1, v1, out1h,
                                                w2, w3, wih, whh, wcls,
                                                w2p, w3p, wihp, whhp, wclsp);

    // conv2: proven M=64 + T14 cs=1 register prefetch (R6 best config)
    conv2_mfma_kernel<<<dim3(64, 16), 256, 0, stream>>>(out1h, w2p, b2, g2, bt2, m2, v2, out2h);

    // fused conv3 + gi: feats never materialized; writes gi2 [bblk][s][g][4] directly
    conv3gi_kernel<<<dim3(32, 16), 256, 0, stream>>>(out2h, w3p, b3, g3, bt3, m3, v3,
                                                     wihp, bih, gi2);

    // GRU scan: EXACT R3 source (proven ~652 us, at structural floor)
    gru_mfma_kernel<<<4, 1024, 0, stream>>>(gi2, whhp, bhh, hsave);

    // classifier over the full h history (parallel, MFMA)
    cls_kernel<<<128, 256, 0, stream>>>(hsave, wclsp, bcls, fout);
}